// Round 1
// baseline (898.578 us; speedup 1.0000x reference)
//
#include <hip/hip_runtime.h>

// Problem constants (fixed by setup_inputs): B=4, N=10, C=256, Hq=Wq=Hs=Ws=32,
// Lq=Ls=1024, K=5, G=N/K=2.
#define CQ_ELEMS (4 * 256 * 1024)    // 1048576 query floats
#define CS_ELEMS (10 * 256 * 1024)   // 2621440 support floats
#define OUT2_OFF 2097152             // flat offset (floats) of 'aligned' in d_out

// ---------------------------------------------------------------------------
// Kernel 1: global scalar means of query and support -> ws[0], ws[1] (sums)
// ---------------------------------------------------------------------------
__global__ __launch_bounds__(256) void means_kernel(const float* __restrict__ q,
                                                    const float* __restrict__ s,
                                                    float* __restrict__ ws) {
    const int tid = blockIdx.x * 256 + threadIdx.x;
    const int stride = gridDim.x * 256;
    float sq = 0.f, ss = 0.f;
    const float4* q4 = (const float4*)q;
    const float4* s4 = (const float4*)s;
    for (int i = tid; i < CQ_ELEMS / 4; i += stride) {
        float4 v = q4[i];
        sq += (v.x + v.y) + (v.z + v.w);
    }
    for (int i = tid; i < CS_ELEMS / 4; i += stride) {
        float4 v = s4[i];
        ss += (v.x + v.y) + (v.z + v.w);
    }
#pragma unroll
    for (int off = 32; off > 0; off >>= 1) {
        sq += __shfl_down(sq, off, 64);
        ss += __shfl_down(ss, off, 64);
    }
    __shared__ float redq[4], reds[4];
    const int lane = threadIdx.x & 63, wid = threadIdx.x >> 6;
    if (lane == 0) { redq[wid] = sq; reds[wid] = ss; }
    __syncthreads();
    if (threadIdx.x == 0) {
        atomicAdd(&ws[0], (redq[0] + redq[1]) + (redq[2] + redq[3]));
        atomicAdd(&ws[1], (reds[0] + reds[1]) + (reds[2] + reds[3]));
    }
}

// ---------------------------------------------------------------------------
// Kernel 2: q_out[b,g,c,l] = Q[b,c,l] - mean_q   (g = 0,1 identical copies)
// ---------------------------------------------------------------------------
__global__ __launch_bounds__(256) void qout_kernel(const float* __restrict__ q,
                                                   const float* __restrict__ ws,
                                                   float* __restrict__ out) {
    const float mq = ws[0] * (1.0f / (float)CQ_ELEMS);
    const int i = blockIdx.x * 256 + threadIdx.x;  // float4 index, 262144 total
    float4 v = ((const float4*)q)[i];
    v.x -= mq; v.y -= mq; v.z -= mq; v.w -= mq;
    const int b = i >> 16;          // 65536 float4 per batch image
    const int r = i & 0xFFFF;
    float4* o = (float4*)out;
    o[(b << 17) + r] = v;           // g = 0
    o[(b << 17) + 65536 + r] = v;   // g = 1
}

// ---------------------------------------------------------------------------
// Kernel 3: fused attention.  One block = one (b,n) pair x 64 q-positions.
//   sim = (Q-mq)^T (S-ms)  [64 q x 1024 s], online softmax over s-tiles of 64,
//   acc[64 q][256 c] += P * (S-ms)^T, epilogue: acc/l * (1/K) atomicAdd'ed
//   into aligned[g][b][c][q].
// LDS: A/Bs are phase-aliased (Qc|ST|Ostage and Sc|PT).  ~35 KB total.
// ---------------------------------------------------------------------------
__global__ __launch_bounds__(256, 2) void attn_kernel(const float* __restrict__ Q,
                                                      const float* __restrict__ S,
                                                      const float* __restrict__ ws,
                                                      float* __restrict__ out) {
    __shared__ float A[64 * 68];   // sim: Qc [c][q] stride 64 | PV: ST [s][c] stride 68 | epi: O [c][q] stride 68
    __shared__ float Bs[64 * 68];  // sim: Sc [c][s] stride 64 | PV: PT [s][q] stride 68

    const int t = threadIdx.x;
    const int q0 = blockIdx.x << 6;   // q tile base (16 tiles)
    const int bn = blockIdx.y;        // 0..39
    const int b = bn / 10;
    const int n = bn - b * 10;
    const int g = n / 5;

    const float mq = ws[0] * (1.0f / (float)CQ_ELEMS);
    const float ms = ws[1] * (1.0f / (float)CS_ELEMS);

    const float* __restrict__ Qb = Q + b * (256 * 1024);
    const float* __restrict__ Sn = S + n * (256 * 1024);

    const int qg = t >> 4;    // 0..15 : q micro-group (rows 4qg..4qg+3) in BOTH phases
    const int g16 = t & 15;   // 0..15 : s-group (sim) / c-group (PV)

    float acc[4][16];         // [qi][cc*4+cj]  -> c = cc*64 + 4*g16 + cj
#pragma unroll
    for (int i = 0; i < 4; ++i)
#pragma unroll
        for (int j = 0; j < 16; ++j) acc[i][j] = 0.f;

    float m_run[4], l_run[4];
#pragma unroll
    for (int i = 0; i < 4; ++i) { m_run[i] = -1e30f; l_run[i] = 0.f; }

    const int lrow = t >> 4;           // staging: base row
    const int lc4 = (t & 15) << 2;     // staging: col base (float4)

    for (int si = 0; si < 16; ++si) {
        const int s0 = si << 6;

        // ---- phase A: sim[4q][4s] over all 256 c (chunks of 64) ----
        float sim[4][4];
#pragma unroll
        for (int i = 0; i < 4; ++i)
#pragma unroll
            for (int j = 0; j < 4; ++j) sim[i][j] = 0.f;

#pragma unroll
        for (int cc = 0; cc < 4; ++cc) {
            __syncthreads();  // previous-phase LDS reads complete
#pragma unroll
            for (int k = 0; k < 4; ++k) {
                const int row = lrow + (k << 4);  // c_local
                float4 v = *(const float4*)(Qb + ((cc << 6) + row) * 1024 + q0 + lc4);
                v.x -= mq; v.y -= mq; v.z -= mq; v.w -= mq;
                *(float4*)(&A[(row << 6) + lc4]) = v;
                float4 w = *(const float4*)(Sn + ((cc << 6) + row) * 1024 + s0 + lc4);
                w.x -= ms; w.y -= ms; w.z -= ms; w.w -= ms;
                *(float4*)(&Bs[(row << 6) + lc4]) = w;
            }
            __syncthreads();
#pragma unroll 4
            for (int j = 0; j < 64; ++j) {
                const float4 qv = *(const float4*)(&A[(j << 6) + (qg << 2)]);
                const float4 sv = *(const float4*)(&Bs[(j << 6) + (g16 << 2)]);
                sim[0][0] += qv.x * sv.x; sim[0][1] += qv.x * sv.y; sim[0][2] += qv.x * sv.z; sim[0][3] += qv.x * sv.w;
                sim[1][0] += qv.y * sv.x; sim[1][1] += qv.y * sv.y; sim[1][2] += qv.y * sv.z; sim[1][3] += qv.y * sv.w;
                sim[2][0] += qv.z * sv.x; sim[2][1] += qv.z * sv.y; sim[2][2] += qv.z * sv.z; sim[2][3] += qv.z * sv.w;
                sim[3][0] += qv.w * sv.x; sim[3][1] += qv.w * sv.y; sim[3][2] += qv.w * sv.z; sim[3][3] += qv.w * sv.w;
            }
        }

        // ---- online softmax update (row stats replicated across the 16 sg lanes) ----
        float rowmax[4];
#pragma unroll
        for (int i = 0; i < 4; ++i)
            rowmax[i] = fmaxf(fmaxf(sim[i][0], sim[i][1]), fmaxf(sim[i][2], sim[i][3]));
#pragma unroll
        for (int off = 1; off <= 8; off <<= 1) {
#pragma unroll
            for (int i = 0; i < 4; ++i)
                rowmax[i] = fmaxf(rowmax[i], __shfl_xor(rowmax[i], off, 64));
        }

        float alpha[4];
#pragma unroll
        for (int i = 0; i < 4; ++i) {
            const float mn = fmaxf(m_run[i], rowmax[i]);
            alpha[i] = __expf(m_run[i] - mn);
            m_run[i] = mn;
        }

        float p[4][4], rs[4];
#pragma unroll
        for (int i = 0; i < 4; ++i) {
            p[i][0] = __expf(sim[i][0] - m_run[i]);
            p[i][1] = __expf(sim[i][1] - m_run[i]);
            p[i][2] = __expf(sim[i][2] - m_run[i]);
            p[i][3] = __expf(sim[i][3] - m_run[i]);
            rs[i] = (p[i][0] + p[i][1]) + (p[i][2] + p[i][3]);
        }
#pragma unroll
        for (int off = 1; off <= 8; off <<= 1) {
#pragma unroll
            for (int i = 0; i < 4; ++i)
                rs[i] += __shfl_xor(rs[i], off, 64);
        }
#pragma unroll
        for (int i = 0; i < 4; ++i)
            l_run[i] = l_run[i] * alpha[i] + rs[i];

#pragma unroll
        for (int i = 0; i < 4; ++i)
#pragma unroll
            for (int j = 0; j < 16; ++j)
                acc[i][j] *= alpha[i];

        // ---- write P transposed: PT[s][q], stride 68 (b128-readable over q) ----
        __syncthreads();  // everyone done reading Sc from Bs
#pragma unroll
        for (int sj = 0; sj < 4; ++sj) {
            float4 pv;
            pv.x = p[0][sj]; pv.y = p[1][sj]; pv.z = p[2][sj]; pv.w = p[3][sj];
            *(float4*)(&Bs[((g16 << 2) + sj) * 68 + (qg << 2)]) = pv;
        }

        // ---- phase B: acc[4q][c-chunk] += P * S^T, S^T staged per 64-c chunk ----
#pragma unroll
        for (int cc = 0; cc < 4; ++cc) {
            __syncthreads();
#pragma unroll
            for (int k = 0; k < 4; ++k) {
                const int row = lrow + (k << 4);  // c_local
                float4 w = *(const float4*)(Sn + ((cc << 6) + row) * 1024 + s0 + lc4);
                A[(lc4 + 0) * 68 + row] = w.x - ms;
                A[(lc4 + 1) * 68 + row] = w.y - ms;
                A[(lc4 + 2) * 68 + row] = w.z - ms;
                A[(lc4 + 3) * 68 + row] = w.w - ms;
            }
            __syncthreads();
#pragma unroll 4
            for (int s = 0; s < 64; ++s) {
                const float4 pv = *(const float4*)(&Bs[s * 68 + (qg << 2)]);
                const float4 sv = *(const float4*)(&A[s * 68 + (g16 << 2)]);
                acc[0][(cc << 2) + 0] += pv.x * sv.x; acc[0][(cc << 2) + 1] += pv.x * sv.y;
                acc[0][(cc << 2) + 2] += pv.x * sv.z; acc[0][(cc << 2) + 3] += pv.x * sv.w;
                acc[1][(cc << 2) + 0] += pv.y * sv.x; acc[1][(cc << 2) + 1] += pv.y * sv.y;
                acc[1][(cc << 2) + 2] += pv.y * sv.z; acc[1][(cc << 2) + 3] += pv.y * sv.w;
                acc[2][(cc << 2) + 0] += pv.z * sv.x; acc[2][(cc << 2) + 1] += pv.z * sv.y;
                acc[2][(cc << 2) + 2] += pv.z * sv.z; acc[2][(cc << 2) + 3] += pv.z * sv.w;
                acc[3][(cc << 2) + 0] += pv.w * sv.x; acc[3][(cc << 2) + 1] += pv.w * sv.y;
                acc[3][(cc << 2) + 2] += pv.w * sv.z; acc[3][(cc << 2) + 3] += pv.w * sv.w;
            }
        }
    }

    // ---- epilogue: stage through LDS for coalesced atomics (K-shot average) ----
    float inv_l[4];
#pragma unroll
    for (int i = 0; i < 4; ++i) inv_l[i] = 0.2f / l_run[i];

    float* __restrict__ out2 = out + OUT2_OFF + (size_t)((g << 2) + b) * (256 * 1024);

#pragma unroll
    for (int cc = 0; cc < 4; ++cc) {
        __syncthreads();
#pragma unroll
        for (int i = 0; i < 4; ++i)
#pragma unroll
            for (int cj = 0; cj < 4; ++cj)
                A[((g16 << 2) + cj) * 68 + (qg << 2) + i] = acc[i][(cc << 2) + cj] * inv_l[i];
        __syncthreads();
#pragma unroll
        for (int k = 0; k < 16; ++k) {
            const int fi = t + (k << 8);     // 0..4095
            const int cl = fi >> 6;          // c_local
            const int qq = fi & 63;          // q (lanes consecutive -> coalesced)
            atomicAdd(out2 + ((cc << 6) + cl) * 1024 + q0 + qq, A[cl * 68 + qq]);
        }
    }
}

// ---------------------------------------------------------------------------
extern "C" void kernel_launch(void* const* d_in, const int* in_sizes, int n_in,
                              void* d_out, int out_size, void* d_ws, size_t ws_size,
                              hipStream_t stream) {
    const float* q = (const float*)d_in[0];
    const float* s = (const float*)d_in[1];
    float* out = (float*)d_out;
    float* ws = (float*)d_ws;

    // zero the mean accumulators and the atomically-accumulated 'aligned' half
    hipMemsetAsync(d_ws, 0, 2 * sizeof(float), stream);
    hipMemsetAsync((char*)d_out + (size_t)OUT2_OFF * 4, 0, (size_t)OUT2_OFF * 4, stream);

    means_kernel<<<256, 256, 0, stream>>>(q, s, ws);
    qout_kernel<<<262144 / 256, 256, 0, stream>>>(q, ws, out);
    attn_kernel<<<dim3(16, 40), 256, 0, stream>>>(q, s, ws, out);
}

// Round 2
// 286.070 us; speedup vs baseline: 3.1411x; 3.1411x over previous
//
#include <hip/hip_runtime.h>

// B=4, N=10, C=256, Lq=Ls=1024, K=5, G=2.  TQ=64, TS=32.
#define CQ_ELEMS (4 * 256 * 1024)
#define CS_ELEMS (10 * 256 * 1024)
#define OUT2_OFF 2097152

typedef __attribute__((ext_vector_type(8))) short short8;
typedef __attribute__((ext_vector_type(4))) float f32x4;
typedef __attribute__((ext_vector_type(4))) short short4v;

__device__ __forceinline__ unsigned short f2bf(float x) {
    unsigned u = __float_as_uint(x);
    u += 0x7FFF + ((u >> 16) & 1);   // RNE to bf16
    return (unsigned short)(u >> 16);
}
__device__ __forceinline__ float bf2f(unsigned short b) {
    return __uint_as_float(((unsigned)b) << 16);
}

// ws layout (bytes): [0..255] float means[2]; then Sh, Sl, Sv (each 10*1024*256 u16)
#define WS_MEANS 0
#define WS_SH 256
#define S_HALF (10 * 1024 * 256)

// ---------------------------------------------------------------------------
__global__ __launch_bounds__(256) void means_kernel(const float* __restrict__ q,
                                                    const float* __restrict__ s,
                                                    float* __restrict__ ws) {
    const int tid = blockIdx.x * 256 + threadIdx.x;
    const int stride = gridDim.x * 256;
    float sq = 0.f, ss = 0.f;
    const float4* q4 = (const float4*)q;
    const float4* s4 = (const float4*)s;
    for (int i = tid; i < CQ_ELEMS / 4; i += stride) {
        float4 v = q4[i];
        sq += (v.x + v.y) + (v.z + v.w);
    }
    for (int i = tid; i < CS_ELEMS / 4; i += stride) {
        float4 v = s4[i];
        ss += (v.x + v.y) + (v.z + v.w);
    }
#pragma unroll
    for (int off = 32; off > 0; off >>= 1) {
        sq += __shfl_down(sq, off, 64);
        ss += __shfl_down(ss, off, 64);
    }
    __shared__ float redq[4], reds[4];
    const int lane = threadIdx.x & 63, wid = threadIdx.x >> 6;
    if (lane == 0) { redq[wid] = sq; reds[wid] = ss; }
    __syncthreads();
    if (threadIdx.x == 0) {
        atomicAdd(&ws[0], (redq[0] + redq[1]) + (redq[2] + redq[3]));
        atomicAdd(&ws[1], (reds[0] + reds[1]) + (reds[2] + reds[3]));
    }
}

// ---------------------------------------------------------------------------
__global__ __launch_bounds__(256) void qout_kernel(const float* __restrict__ q,
                                                   const float* __restrict__ ws,
                                                   float* __restrict__ out) {
    const float mq = ws[0] * (1.0f / (float)CQ_ELEMS);
    const int i = blockIdx.x * 256 + threadIdx.x;
    float4 v = ((const float4*)q)[i];
    v.x -= mq; v.y -= mq; v.z -= mq; v.w -= mq;
    const int b = i >> 16;
    const int r = i & 0xFFFF;
    float4* o = (float4*)out;
    o[(b << 17) + r] = v;
    o[(b << 17) + 65536 + r] = v;
}

// ---------------------------------------------------------------------------
// Convert centered S to bf16:  Sh/Sl[n][s][c] (c-contig, hi/lo split) and
// Sv[n][c][s] (s-contig, hi only).  32x32 LDS tile transpose per block.
// ---------------------------------------------------------------------------
__global__ __launch_bounds__(256) void convert_kernel(const float* __restrict__ S,
                                                      const float* __restrict__ ws,
                                                      unsigned short* __restrict__ sh,
                                                      unsigned short* __restrict__ slo,
                                                      unsigned short* __restrict__ sv) {
    __shared__ unsigned short Th[32][33], Tl[32][33];
    const int t = threadIdx.x;
    const int s0 = blockIdx.x << 5;   // 32 tiles
    const int c0 = blockIdx.y << 5;   // 8 tiles
    const int n = blockIdx.z;         // 10
    const float ms = ws[1] * (1.0f / (float)CS_ELEMS);

    {
        const int cl = t >> 3, s4 = (t & 7) << 2;
        float4 v = *(const float4*)(S + ((size_t)(n * 256 + c0 + cl)) * 1024 + s0 + s4);
        float x[4] = {v.x - ms, v.y - ms, v.z - ms, v.w - ms};
        unsigned short hb[4], lb[4];
#pragma unroll
        for (int j = 0; j < 4; ++j) {
            hb[j] = f2bf(x[j]);
            lb[j] = f2bf(x[j] - bf2f(hb[j]));
        }
        short4v hv; hv.x = (short)hb[0]; hv.y = (short)hb[1]; hv.z = (short)hb[2]; hv.w = (short)hb[3];
        *(short4v*)(sv + ((size_t)(n * 256 + c0 + cl)) * 1024 + s0 + s4) = hv;
#pragma unroll
        for (int j = 0; j < 4; ++j) { Th[cl][s4 + j] = hb[j]; Tl[cl][s4 + j] = lb[j]; }
    }
    __syncthreads();
    {
        const int sl_ = t >> 3, c4 = (t & 7) << 2;
        short4v hv, lv;
        hv.x = (short)Th[c4 + 0][sl_]; hv.y = (short)Th[c4 + 1][sl_];
        hv.z = (short)Th[c4 + 2][sl_]; hv.w = (short)Th[c4 + 3][sl_];
        lv.x = (short)Tl[c4 + 0][sl_]; lv.y = (short)Tl[c4 + 1][sl_];
        lv.z = (short)Tl[c4 + 2][sl_]; lv.w = (short)Tl[c4 + 3][sl_];
        *(short4v*)(sh + ((size_t)(n * 1024 + s0 + sl_)) * 256 + c0 + c4) = hv;
        *(short4v*)(slo + ((size_t)(n * 1024 + s0 + sl_)) * 256 + c0 + c4) = lv;
    }
}

// ---------------------------------------------------------------------------
// Fused flash attention with MFMA.  Block = (q-tile of 64, bn pair), 4 waves.
// QK^T in split-bf16 (3 MFMA), PV in plain bf16.  16x16x32 MFMAs.
// ---------------------------------------------------------------------------
union __align__(16) SMem {
    struct {
        unsigned short s1h[32][264];  // S-tile hi, [s][c], row 528 B (16B-mult, bank-spread)
        unsigned short s1l[32][264];  // S-tile lo
        unsigned short s2[256][40];   // V-tile, [c][s], row 80 B
        unsigned short pb[64][40];    // P, [q][s], row 80 B
    } st;
    float epi[2][64][68];             // epilogue staging (aliases the above)
};

__global__ __launch_bounds__(256, 2) void attn_kernel(const float* __restrict__ Q,
                                                      const unsigned short* __restrict__ sh,
                                                      const unsigned short* __restrict__ slo,
                                                      const unsigned short* __restrict__ sv,
                                                      const float* __restrict__ ws,
                                                      float* __restrict__ out) {
    __shared__ SMem sm;
    __shared__ float alpha_s[64];
    __shared__ float lfin[64];

    const int t = threadIdx.x;
    const int w = t >> 6;
    const int lane = t & 63;
    const int quad = lane >> 4;
    const int l16 = lane & 15;

    const int q0 = blockIdx.x << 6;   // 16 q-tiles
    const int bn = blockIdx.y;        // 40
    const int b = bn / 10;
    const int n = bn - b * 10;
    const int g = n / 5;

    const float mq = ws[0] * (1.0f / (float)CQ_ELEMS);

    const unsigned short* __restrict__ Shn = sh + (size_t)n * (1024 * 256);
    const unsigned short* __restrict__ Sln = slo + (size_t)n * (1024 * 256);
    const unsigned short* __restrict__ Svn = sv + (size_t)n * (256 * 1024);
    const float* __restrict__ Qb = Q + (size_t)b * (256 * 1024);

    // ---- preload Q A-frags (wave w owns q rows q0+16w .. +15), hi/lo split ----
    short8 qh[8], ql[8];
    {
        const float* qp = Qb + q0 + 16 * w + l16;
#pragma unroll
        for (int f = 0; f < 8; ++f) {
#pragma unroll
            for (int j = 0; j < 8; ++j) {
                float x = qp[(size_t)(32 * f + 8 * quad + j) * 1024] - mq;
                unsigned short hb = f2bf(x);
                qh[f][j] = (short)hb;
                ql[f][j] = (short)f2bf(x - bf2f(hb));
            }
        }
    }

    f32x4 O[4][4];   // PV acc: rows q=16mt+.., cols c=64w+16nt+..
#pragma unroll
    for (int mt = 0; mt < 4; ++mt)
#pragma unroll
        for (int nt = 0; nt < 4; ++nt) O[mt][nt] = (f32x4){0.f, 0.f, 0.f, 0.f};

    float m_run[4], l_run[4];
#pragma unroll
    for (int r = 0; r < 4; ++r) { m_run[r] = -1e30f; l_run[r] = 0.f; }

    const int srow = t >> 3, ch = t & 7;   // S1 staging map
    const int c4 = t >> 2, ck = t & 3;     // S2 staging map

    for (int s0i = 0; s0i < 32; ++s0i) {
        const int s0 = s0i << 5;
        __syncthreads();   // prior-step LDS reads complete

        // ---- stage S1h/S1l ([s][c] padded rows) and S2 ([c][s] padded rows) ----
        {
            const unsigned short* gh = Shn + (size_t)(s0 + srow) * 256;
            const unsigned short* gl = Sln + (size_t)(s0 + srow) * 256;
#pragma unroll
            for (int it = 0; it < 4; ++it) {
                const int cu = ch + 8 * it;
                *(short8*)&sm.st.s1h[srow][cu * 8] = *(const short8*)(gh + cu * 8);
                *(short8*)&sm.st.s1l[srow][cu * 8] = *(const short8*)(gl + cu * 8);
            }
#pragma unroll
            for (int it = 0; it < 4; ++it) {
                const int c = c4 + 64 * it;
                *(short8*)&sm.st.s2[c][ck * 8] =
                    *(const short8*)(Svn + (size_t)c * 1024 + s0 + ck * 8);
            }
        }
        __syncthreads();

        // ---- QK^T: sim[16q x 32s], split bf16 (hi*hi + lo*hi + hi*lo) ----
        f32x4 sim[2];
        sim[0] = (f32x4){0.f, 0.f, 0.f, 0.f};
        sim[1] = (f32x4){0.f, 0.f, 0.f, 0.f};
#pragma unroll
        for (int f = 0; f < 8; ++f) {
#pragma unroll
            for (int nt = 0; nt < 2; ++nt) {
                const int srw = nt * 16 + l16;
                short8 bh = *(const short8*)&sm.st.s1h[srw][(f * 4 + quad) * 8];
                short8 bl = *(const short8*)&sm.st.s1l[srw][(f * 4 + quad) * 8];
                sim[nt] = __builtin_amdgcn_mfma_f32_16x16x32_bf16(qh[f], bh, sim[nt], 0, 0, 0);
                sim[nt] = __builtin_amdgcn_mfma_f32_16x16x32_bf16(ql[f], bh, sim[nt], 0, 0, 0);
                sim[nt] = __builtin_amdgcn_mfma_f32_16x16x32_bf16(qh[f], bl, sim[nt], 0, 0, 0);
            }
        }

        // ---- online softmax (rows 4*quad+r of wave's 16 q; reduce over 16 lanes) ----
        float rowmax[4];
#pragma unroll
        for (int r = 0; r < 4; ++r) rowmax[r] = fmaxf(sim[0][r], sim[1][r]);
#pragma unroll
        for (int off = 1; off <= 8; off <<= 1)
#pragma unroll
            for (int r = 0; r < 4; ++r)
                rowmax[r] = fmaxf(rowmax[r], __shfl_xor(rowmax[r], off, 64));

        float al[4], rs[4], pv[2][4];
#pragma unroll
        for (int r = 0; r < 4; ++r) {
            const float mn = fmaxf(m_run[r], rowmax[r]);
            al[r] = __expf(m_run[r] - mn);
            m_run[r] = mn;
            pv[0][r] = __expf(sim[0][r] - mn);
            pv[1][r] = __expf(sim[1][r] - mn);
            rs[r] = pv[0][r] + pv[1][r];
        }
#pragma unroll
        for (int off = 1; off <= 8; off <<= 1)
#pragma unroll
            for (int r = 0; r < 4; ++r) rs[r] += __shfl_xor(rs[r], off, 64);
#pragma unroll
        for (int r = 0; r < 4; ++r) l_run[r] = l_run[r] * al[r] + rs[r];

        // ---- publish P (bf16, [q][s]) and alpha ----
#pragma unroll
        for (int nt = 0; nt < 2; ++nt)
#pragma unroll
            for (int r = 0; r < 4; ++r)
                sm.st.pb[16 * w + 4 * quad + r][nt * 16 + l16] = f2bf(pv[nt][r]);
        if (l16 == 0) {
#pragma unroll
            for (int r = 0; r < 4; ++r) alpha_s[16 * w + 4 * quad + r] = al[r];
        }
        __syncthreads();

        // ---- rescale O by alpha, then PV: O[64q x 64c-slice] += P * V ----
#pragma unroll
        for (int mt = 0; mt < 4; ++mt) {
#pragma unroll
            for (int r = 0; r < 4; ++r) {
                const float a = alpha_s[16 * mt + 4 * quad + r];
                O[mt][0][r] *= a; O[mt][1][r] *= a; O[mt][2][r] *= a; O[mt][3][r] *= a;
            }
        }
        short8 vf[4];
#pragma unroll
        for (int nt = 0; nt < 4; ++nt)
            vf[nt] = *(const short8*)&sm.st.s2[64 * w + 16 * nt + l16][quad * 8];
#pragma unroll
        for (int mt = 0; mt < 4; ++mt) {
            short8 pf = *(const short8*)&sm.st.pb[16 * mt + l16][quad * 8];
#pragma unroll
            for (int nt = 0; nt < 4; ++nt)
                O[mt][nt] = __builtin_amdgcn_mfma_f32_16x16x32_bf16(pf, vf[nt], O[mt][nt], 0, 0, 0);
        }
    }

    // ---- epilogue: O / l * (1/K), stage via LDS, coalesced atomics ----
    if (l16 == 0) {
#pragma unroll
        for (int r = 0; r < 4; ++r) lfin[16 * w + 4 * quad + r] = l_run[r];
    }
    __syncthreads();

    float linv[4][4];
#pragma unroll
    for (int mt = 0; mt < 4; ++mt)
#pragma unroll
        for (int r = 0; r < 4; ++r) linv[mt][r] = 0.2f / lfin[16 * mt + 4 * quad + r];

    float* __restrict__ out2 = out + OUT2_OFF + (size_t)((g << 2) + b) * (256 * 1024);

#pragma unroll
    for (int half = 0; half < 2; ++half) {
        if ((w >> 1) == half) {
            const int we = w & 1;
#pragma unroll
            for (int mt = 0; mt < 4; ++mt)
#pragma unroll
                for (int nt = 0; nt < 4; ++nt)
#pragma unroll
                    for (int r = 0; r < 4; ++r)
                        sm.epi[we][16 * nt + l16][16 * mt + 4 * quad + r] = O[mt][nt][r] * linv[mt][r];
        }
        __syncthreads();
#pragma unroll 4
        for (int i = 0; i < 32; ++i) {
            const int ro = w * 32 + i;   // 0..127 -> c = 128*half + ro
            const float v = sm.epi[ro >> 6][ro & 63][lane];
            atomicAdd(out2 + (size_t)(half * 128 + ro) * 1024 + q0 + lane, v);
        }
        __syncthreads();
    }
}

// ---------------------------------------------------------------------------
extern "C" void kernel_launch(void* const* d_in, const int* in_sizes, int n_in,
                              void* d_out, int out_size, void* d_ws, size_t ws_size,
                              hipStream_t stream) {
    const float* q = (const float*)d_in[0];
    const float* s = (const float*)d_in[1];
    float* out = (float*)d_out;
    float* ws = (float*)d_ws;
    unsigned short* sh = (unsigned short*)((char*)d_ws + WS_SH);
    unsigned short* slo = sh + S_HALF;
    unsigned short* sv = slo + S_HALF;

    hipMemsetAsync(d_ws, 0, 2 * sizeof(float), stream);
    hipMemsetAsync((char*)d_out + (size_t)OUT2_OFF * 4, 0, (size_t)OUT2_OFF * 4, stream);

    means_kernel<<<256, 256, 0, stream>>>(q, s, ws);
    qout_kernel<<<262144 / 256, 256, 0, stream>>>(q, ws, out);
    convert_kernel<<<dim3(32, 8, 10), 256, 0, stream>>>(s, ws, sh, slo, sv);
    attn_kernel<<<dim3(16, 40), 256, 0, stream>>>(q, sh, slo, sv, ws, out);
}

// Round 3
// 242.355 us; speedup vs baseline: 3.7077x; 1.1804x over previous
//
#include <hip/hip_runtime.h>

// B=4, N=10, C=256, Lq=Ls=1024, K=5, G=2.  TQ=64, TS=32.  fp16 MFMA path.
#define CQ_ELEMS (4 * 256 * 1024)
#define CS_ELEMS (10 * 256 * 1024)
#define OUT2_OFF 2097152

typedef __attribute__((ext_vector_type(8))) _Float16 f16x8;
typedef __attribute__((ext_vector_type(4))) float f32x4;

// ws layout (bytes): [0..255] float means[2];
//   Sh[n][s][c] fp16 (10*1024*256), Sv[n][c][s] fp16 (10*256*1024), Qt[b][q][c] fp16 (4*1024*256)
#define WS_SH 256
#define SH_ELEMS (10 * 1024 * 256)
#define SV_ELEMS (10 * 256 * 1024)

// ---------------------------------------------------------------------------
__global__ __launch_bounds__(256) void means_kernel(const float* __restrict__ q,
                                                    const float* __restrict__ s,
                                                    float* __restrict__ ws) {
    const int tid = blockIdx.x * 256 + threadIdx.x;
    const int stride = gridDim.x * 256;
    float sq = 0.f, ss = 0.f;
    const float4* q4 = (const float4*)q;
    const float4* s4 = (const float4*)s;
    for (int i = tid; i < CQ_ELEMS / 4; i += stride) {
        float4 v = q4[i];
        sq += (v.x + v.y) + (v.z + v.w);
    }
    for (int i = tid; i < CS_ELEMS / 4; i += stride) {
        float4 v = s4[i];
        ss += (v.x + v.y) + (v.z + v.w);
    }
#pragma unroll
    for (int off = 32; off > 0; off >>= 1) {
        sq += __shfl_down(sq, off, 64);
        ss += __shfl_down(ss, off, 64);
    }
    __shared__ float redq[4], reds[4];
    const int lane = threadIdx.x & 63, wid = threadIdx.x >> 6;
    if (lane == 0) { redq[wid] = sq; reds[wid] = ss; }
    __syncthreads();
    if (threadIdx.x == 0) {
        atomicAdd(&ws[0], (redq[0] + redq[1]) + (redq[2] + redq[3]));
        atomicAdd(&ws[1], (reds[0] + reds[1]) + (reds[2] + reds[3]));
    }
}

// ---------------------------------------------------------------------------
// Centered fp16 conversion.  z<10: S -> Sv [c][s] + Sh [s][c] (transposed).
// z>=10: Q -> q_out (fp32, both g-copies) + Qt [q][c] (transposed).
// ---------------------------------------------------------------------------
__global__ __launch_bounds__(256) void convert_kernel(const float* __restrict__ Q,
                                                      const float* __restrict__ S,
                                                      const float* __restrict__ ws,
                                                      unsigned short* __restrict__ sh,
                                                      unsigned short* __restrict__ sv,
                                                      unsigned short* __restrict__ qt,
                                                      float* __restrict__ out) {
    __shared__ unsigned short Th[32][40];
    const int t = threadIdx.x;
    const int x0 = blockIdx.x << 5;   // s (or q) tile base
    const int c0 = blockIdx.y << 5;   // c tile base
    const int z = blockIdx.z;

    const int cl = t >> 3, x4 = (t & 7) << 2;

    if (z < 10) {
        const int n = z;
        const float ms = ws[1] * (1.0f / (float)CS_ELEMS);
        float4 v = *(const float4*)(S + ((size_t)(n * 256 + c0 + cl)) * 1024 + x0 + x4);
        float x[4] = {v.x - ms, v.y - ms, v.z - ms, v.w - ms};
        unsigned short hb[4];
#pragma unroll
        for (int j = 0; j < 4; ++j) {
            _Float16 h = (_Float16)x[j];
            hb[j] = __builtin_bit_cast(unsigned short, h);
            Th[cl][x4 + j] = hb[j];
        }
        *(ushort4*)(sv + ((size_t)(n * 256 + c0 + cl)) * 1024 + x0 + x4) =
            make_ushort4(hb[0], hb[1], hb[2], hb[3]);
        __syncthreads();
        const int sl = t >> 3, c4 = (t & 7) << 2;
        *(ushort4*)(sh + ((size_t)(n * 1024 + x0 + sl)) * 256 + c0 + c4) =
            make_ushort4(Th[c4 + 0][sl], Th[c4 + 1][sl], Th[c4 + 2][sl], Th[c4 + 3][sl]);
    } else {
        const int b = z - 10;
        const float mq = ws[0] * (1.0f / (float)CQ_ELEMS);
        float4 v = *(const float4*)(Q + ((size_t)(b * 256 + c0 + cl)) * 1024 + x0 + x4);
        v.x -= mq; v.y -= mq; v.z -= mq; v.w -= mq;
        // q_out: [B][2][C][1024], both g copies
        float* o = out + ((size_t)(b * 2) * 256 + (c0 + cl)) * 1024 + x0 + x4;
        *(float4*)o = v;
        *(float4*)(o + 256 * 1024) = v;
        float x[4] = {v.x, v.y, v.z, v.w};
#pragma unroll
        for (int j = 0; j < 4; ++j) {
            _Float16 h = (_Float16)x[j];
            Th[cl][x4 + j] = __builtin_bit_cast(unsigned short, h);
        }
        __syncthreads();
        const int ql = t >> 3, c4 = (t & 7) << 2;
        *(ushort4*)(qt + ((size_t)(b * 1024 + x0 + ql)) * 256 + c0 + c4) =
            make_ushort4(Th[c4 + 0][ql], Th[c4 + 1][ql], Th[c4 + 2][ql], Th[c4 + 3][ql]);
    }
}

// ---------------------------------------------------------------------------
// Fused flash attention, fp16 MFMA.  Block = (64-q tile, bn pair), 4 waves.
// s1 holds S-tile [s][c] with even/odd s-row permutation (lds row r <-> true
// s = 2*(r&15) + (r>>4)) and 64B-chunk XOR swizzle.  PV computed as
// O^T = V^T * P^T (A from s2 [c][s], B from pb [q][s], both b128).
// ---------------------------------------------------------------------------
union __align__(16) SMem {
    struct {
        unsigned short s1[32][264];  // S-tile fp16 [s-perm][c], 528 B rows, XOR-swizzled 64B chunks
        unsigned short s2[256][40];  // V-tile fp16 [c][s], 80 B rows
        unsigned short pb[64][40];   // P fp16 [q][s], 80 B rows
    } st;
    float epi[2][64][68];            // epilogue staging (aliases)
};

__global__ __launch_bounds__(256, 3) void attn_kernel(const unsigned short* __restrict__ qt,
                                                      const unsigned short* __restrict__ sh,
                                                      const unsigned short* __restrict__ sv,
                                                      float* __restrict__ out) {
    __shared__ SMem sm;
    __shared__ float alpha_s[64];
    __shared__ float lfin[64];

    const int t = threadIdx.x;
    const int w = t >> 6;
    const int lane = t & 63;
    const int quad = lane >> 4;
    const int l16 = lane & 15;

    const int q0 = blockIdx.x << 6;   // 16 q-tiles
    const int bn = blockIdx.y;        // 40
    const int b = bn / 10;
    const int n = bn - b * 10;
    const int g = n / 5;

    const unsigned short* __restrict__ Shn = sh + (size_t)n * (1024 * 256);
    const unsigned short* __restrict__ Svn = sv + (size_t)n * (256 * 1024);

    // ---- Q A-frags: wave w owns q rows q0+16w .. +15 (fp16, pre-transposed) ----
    f16x8 qf[8];
    {
        const unsigned short* qp = qt + (size_t)(b * 1024 + q0 + 16 * w + l16) * 256 + quad * 8;
#pragma unroll
        for (int f = 0; f < 8; ++f)
            qf[f] = *(const f16x8*)(qp + f * 32);
    }

    f32x4 O[4][4];   // O^T: c = 64w+16mt+4quad+r, q = 16nt+l16
#pragma unroll
    for (int mt = 0; mt < 4; ++mt)
#pragma unroll
        for (int nt = 0; nt < 4; ++nt) O[mt][nt] = (f32x4){0.f, 0.f, 0.f, 0.f};

    float m_run[4], l_run[4];
#pragma unroll
    for (int r = 0; r < 4; ++r) { m_run[r] = -1e30f; l_run[r] = 0.f; }

    const int srow = t >> 3;                       // s1 staging: global s row
    const int prow = ((srow & 1) << 4) | (srow >> 1);  // permuted LDS row
    const int c4 = t >> 2, ck = t & 3;             // s2 staging map

    for (int s0i = 0; s0i < 32; ++s0i) {
        const int s0 = s0i << 5;
        __syncthreads();   // prior-step LDS reads complete

        // ---- stage s1 (perm + swizzle) and s2 ----
        {
            const unsigned short* gs = Shn + (size_t)(s0 + srow) * 256;
#pragma unroll
            for (int it = 0; it < 4; ++it) {
                const int u = (t & 7) + 8 * it;          // 16B unit, 0..31
                const int up = (((u >> 2) ^ (prow & 7)) << 2) | (u & 3);
                *(int4*)&sm.st.s1[prow][up * 8] = *(const int4*)(gs + u * 8);
            }
#pragma unroll
            for (int it = 0; it < 4; ++it) {
                const int c = c4 + 64 * it;
                *(int4*)&sm.st.s2[c][ck * 8] =
                    *(const int4*)(Svn + (size_t)c * 1024 + s0 + ck * 8);
            }
        }
        __syncthreads();

        // ---- QK^T: sim[16q x 32s], single fp16 MFMA per chunk ----
        f32x4 sim[2];
        sim[0] = (f32x4){0.f, 0.f, 0.f, 0.f};
        sim[1] = (f32x4){0.f, 0.f, 0.f, 0.f};
#pragma unroll
        for (int f = 0; f < 8; ++f) {
#pragma unroll
            for (int nt = 0; nt < 2; ++nt) {
                const int row = nt * 16 + l16;
                const int uu = ((f ^ (l16 & 7)) << 2) + quad;
                f16x8 bfrag = *(const f16x8*)&sm.st.s1[row][uu * 8];
                sim[nt] = __builtin_amdgcn_mfma_f32_16x16x32_f16(qf[f], bfrag, sim[nt], 0, 0, 0);
            }
        }

        // ---- online softmax (rows q = 16w+4quad+r; reduce over 16 l16 lanes) ----
        float rowmax[4];
#pragma unroll
        for (int r = 0; r < 4; ++r) rowmax[r] = fmaxf(sim[0][r], sim[1][r]);
#pragma unroll
        for (int off = 1; off <= 8; off <<= 1)
#pragma unroll
            for (int r = 0; r < 4; ++r)
                rowmax[r] = fmaxf(rowmax[r], __shfl_xor(rowmax[r], off, 64));

        float al[4], rs[4], pv0[4], pv1[4];
#pragma unroll
        for (int r = 0; r < 4; ++r) {
            const float mn = fmaxf(m_run[r], rowmax[r]);
            al[r] = __expf(m_run[r] - mn);
            m_run[r] = mn;
            pv0[r] = __expf(sim[0][r] - mn);   // true s = 2*l16
            pv1[r] = __expf(sim[1][r] - mn);   // true s = 2*l16+1
            rs[r] = pv0[r] + pv1[r];
        }
#pragma unroll
        for (int off = 1; off <= 8; off <<= 1)
#pragma unroll
            for (int r = 0; r < 4; ++r) rs[r] += __shfl_xor(rs[r], off, 64);
#pragma unroll
        for (int r = 0; r < 4; ++r) l_run[r] = l_run[r] * al[r] + rs[r];

        // ---- publish P (fp16 pairs, b32) and alpha ----
#pragma unroll
        for (int r = 0; r < 4; ++r) {
            union { _Float16 h[2]; unsigned u; } pk;
            pk.h[0] = (_Float16)pv0[r];
            pk.h[1] = (_Float16)pv1[r];
            *(unsigned*)&sm.st.pb[16 * w + 4 * quad + r][l16 * 2] = pk.u;
        }
        if (l16 == 0) {
#pragma unroll
            for (int r = 0; r < 4; ++r) alpha_s[16 * w + 4 * quad + r] = al[r];
        }
        __syncthreads();

        // ---- rescale O^T, then O^T += V^T * P^T ----
#pragma unroll
        for (int nt = 0; nt < 4; ++nt) {
            const float a = alpha_s[16 * nt + l16];
#pragma unroll
            for (int mt = 0; mt < 4; ++mt) {
                O[mt][nt][0] *= a; O[mt][nt][1] *= a; O[mt][nt][2] *= a; O[mt][nt][3] *= a;
            }
        }
        f16x8 vf[4], pf[4];
#pragma unroll
        for (int mt = 0; mt < 4; ++mt)
            vf[mt] = *(const f16x8*)&sm.st.s2[64 * w + 16 * mt + l16][quad * 8];
#pragma unroll
        for (int nt = 0; nt < 4; ++nt)
            pf[nt] = *(const f16x8*)&sm.st.pb[16 * nt + l16][quad * 8];
#pragma unroll
        for (int mt = 0; mt < 4; ++mt)
#pragma unroll
            for (int nt = 0; nt < 4; ++nt)
                O[mt][nt] = __builtin_amdgcn_mfma_f32_16x16x32_f16(vf[mt], pf[nt], O[mt][nt], 0, 0, 0);
    }

    // ---- epilogue ----
    if (l16 == 0) {
#pragma unroll
        for (int r = 0; r < 4; ++r) lfin[16 * w + 4 * quad + r] = l_run[r];
    }
    __syncthreads();

    float linv[4];
#pragma unroll
    for (int nt = 0; nt < 4; ++nt) linv[nt] = 0.2f / lfin[16 * nt + l16];

    float* __restrict__ out2 = out + OUT2_OFF + (size_t)((g << 2) + b) * (256 * 1024);

#pragma unroll
    for (int h = 0; h < 2; ++h) {
        if ((w >> 1) == h) {
            const int we = w & 1;
#pragma unroll
            for (int mt = 0; mt < 4; ++mt)
#pragma unroll
                for (int nt = 0; nt < 4; ++nt)
#pragma unroll
                    for (int r = 0; r < 4; ++r)
                        sm.epi[we][16 * mt + 4 * quad + r][16 * nt + l16] = O[mt][nt][r] * linv[nt];
        }
        __syncthreads();
#pragma unroll 4
        for (int i = 0; i < 32; ++i) {
            const int ro = w * 32 + i;   // 0..127 -> c = 128h + ro
            const float v = sm.epi[ro >> 6][ro & 63][lane];
            atomicAdd(out2 + (size_t)(h * 128 + ro) * 1024 + q0 + lane, v);
        }
        __syncthreads();
    }
}

// ---------------------------------------------------------------------------
extern "C" void kernel_launch(void* const* d_in, const int* in_sizes, int n_in,
                              void* d_out, int out_size, void* d_ws, size_t ws_size,
                              hipStream_t stream) {
    const float* q = (const float*)d_in[0];
    const float* s = (const float*)d_in[1];
    float* out = (float*)d_out;
    float* ws = (float*)d_ws;
    unsigned short* sh = (unsigned short*)((char*)d_ws + WS_SH);
    unsigned short* sv = sh + SH_ELEMS;
    unsigned short* qt = sv + SV_ELEMS;

    hipMemsetAsync(d_ws, 0, 2 * sizeof(float), stream);
    hipMemsetAsync((char*)d_out + (size_t)OUT2_OFF * 4, 0, (size_t)OUT2_OFF * 4, stream);

    means_kernel<<<256, 256, 0, stream>>>(q, s, ws);
    convert_kernel<<<dim3(32, 8, 14), 256, 0, stream>>>(q, s, ws, sh, sv, qt, out);
    attn_kernel<<<dim3(16, 40), 256, 0, stream>>>(qt, sh, sv, out);
}